// Round 2
// baseline (5333.188 us; speedup 1.0000x reference)
//
#include <hip/hip_runtime.h>
#include <hip/hip_bf16.h>

#define N_NODES 100000
#define N_EDGES 3200000
#define N_GRAPHS 256

typedef __hip_bfloat16 bf16;

__device__ __forceinline__ float ldf(const float* p) { return *p; }
__device__ __forceinline__ float ldf(const bf16* p) { return __bfloat162float(*p); }

// ------------------------------------------------------------------
// CSR build: histogram -> exclusive scan -> placement
// ------------------------------------------------------------------
__global__ void hist_kernel(const int* __restrict__ dst, int* __restrict__ cnt) {
    int i = blockIdx.x * blockDim.x + threadIdx.x;
    if (i < N_EDGES) atomicAdd(&cnt[dst[i]], 1);
}

__global__ __launch_bounds__(1024) void scan_kernel(const int* __restrict__ cnt,
                                                    int* __restrict__ rowptr) {
    __shared__ int buf[1024];
    __shared__ int carry;
    if (threadIdx.x == 0) carry = 0;
    __syncthreads();
    for (int base = 0; base < N_NODES; base += 1024) {
        int i = base + threadIdx.x;
        int v = (i < N_NODES) ? cnt[i] : 0;
        buf[threadIdx.x] = v;
        __syncthreads();
        for (int off = 1; off < 1024; off <<= 1) {
            int t = (threadIdx.x >= off) ? buf[threadIdx.x - off] : 0;
            __syncthreads();
            buf[threadIdx.x] += t;
            __syncthreads();
        }
        int excl = carry + buf[threadIdx.x] - v;
        if (i < N_NODES) rowptr[i] = excl;
        __syncthreads();                 // everyone has read carry
        if (threadIdx.x == 0) carry += buf[1023];
        __syncthreads();
    }
    if (threadIdx.x == 0) rowptr[N_NODES] = carry;
}

__global__ void invdeg_kernel(const int* __restrict__ rowptr, float* __restrict__ invdeg) {
    int n = blockIdx.x * blockDim.x + threadIdx.x;
    if (n < N_NODES) {
        int d = rowptr[n + 1] - rowptr[n];
        invdeg[n] = 1.0f / fmaxf((float)d, 1.0f);
    }
}

__global__ void copycur_kernel(const int* __restrict__ rowptr, int* __restrict__ cursor) {
    int n = blockIdx.x * blockDim.x + threadIdx.x;
    if (n < N_NODES) cursor[n] = rowptr[n];
}

__global__ void place_kernel(const int* __restrict__ src, const int* __restrict__ dst,
                             int* __restrict__ cursor, int* __restrict__ cols) {
    int e = blockIdx.x * blockDim.x + threadIdx.x;
    if (e < N_EDGES) {
        int p = atomicAdd(&cursor[dst[e]], 1);
        cols[p] = src[e];
    }
}

// ------------------------------------------------------------------
// gather aggregation: agg[n][f] = bf16( invdeg[n] * sum_j h[cols[j]][f] )
// one block per node, thread = feature
// ------------------------------------------------------------------
template <typename T, int D>
__global__ void agg_kernel(const T* __restrict__ h, const int* __restrict__ rowptr,
                           const int* __restrict__ cols, const float* __restrict__ invdeg,
                           bf16* __restrict__ agg) {
    int n = blockIdx.x;
    int f = threadIdx.x;
    int s = rowptr[n], e = rowptr[n + 1];
    if (f < D) {
        float sum = 0.f;
        for (int j = s; j < e; ++j) {
            int c = cols[j];
            sum += ldf(&h[(long long)c * D + f]);
        }
        agg[(long long)n * D + f] = __float2bfloat16(sum * invdeg[n]);
    }
}

// ------------------------------------------------------------------
// fused SAGE GEMM: r = act( agg @ wl.T + xin @ wr.T + b )
// POOL=0: store bf16 to out.   POOL=1: atomicAdd into pooled[batch[n]].
// ACT: 0 = leaky_relu(0.01), 1 = relu
// 64x64 tile, BK=16, 256 threads, 4x4 micro-tile, fp32 compute
// ------------------------------------------------------------------
template <typename TA, typename TX, int ACT, int POOL>
__global__ __launch_bounds__(256) void sage_gemm(
        const TA* __restrict__ agg, const TX* __restrict__ xin,
        const float* __restrict__ wl, const float* __restrict__ wr,
        const float* __restrict__ bias, bf16* __restrict__ out,
        const int* __restrict__ batch, float* __restrict__ pooled,
        int M, int Din, int Dout) {
    __shared__ float As[16][68];   // [k][row] agg
    __shared__ float Axs[16][68];  // [k][row] x
    __shared__ float Bls[16][68];  // [k][col] wl
    __shared__ float Brs[16][68];  // [k][col] wr

    const int lid = threadIdx.x;
    const int tx = lid & 15;
    const int ty = lid >> 4;
    const int n0 = blockIdx.y * 64;
    const int o0 = blockIdx.x * 64;

    float acc[4][4] = {};

    for (int k0 = 0; k0 < Din; k0 += 16) {
        const int k = k0 + tx;
        const bool kok = (k < Din);
#pragma unroll
        for (int r = 0; r < 4; ++r) {
            int nl = ty + 16 * r;
            int n = n0 + nl;
            float ag = 0.f, xx = 0.f;
            if (kok && n < M) {
                ag = ldf(&agg[(long long)n * Din + k]);
                xx = ldf(&xin[(long long)n * Din + k]);
            }
            As[tx][nl] = ag;
            Axs[tx][nl] = xx;
            int o = o0 + nl;   // Dout is a multiple of 64
            float bl = 0.f, br = 0.f;
            if (kok) {
                bl = wl[(long long)o * Din + k];
                br = wr[(long long)o * Din + k];
            }
            Bls[tx][nl] = bl;
            Brs[tx][nl] = br;
        }
        __syncthreads();
#pragma unroll
        for (int kk = 0; kk < 16; ++kk) {
            float4 aA = *(const float4*)&As[kk][ty * 4];
            float4 aX = *(const float4*)&Axs[kk][ty * 4];
            float4 bL = *(const float4*)&Bls[kk][tx * 4];
            float4 bR = *(const float4*)&Brs[kk][tx * 4];
            const float a_[4] = {aA.x, aA.y, aA.z, aA.w};
            const float x_[4] = {aX.x, aX.y, aX.z, aX.w};
            const float l_[4] = {bL.x, bL.y, bL.z, bL.w};
            const float r_[4] = {bR.x, bR.y, bR.z, bR.w};
#pragma unroll
            for (int i = 0; i < 4; ++i)
#pragma unroll
                for (int j = 0; j < 4; ++j)
                    acc[i][j] += a_[i] * l_[j] + x_[i] * r_[j];
        }
        __syncthreads();
    }

#pragma unroll
    for (int i = 0; i < 4; ++i) {
        int n = n0 + ty * 4 + i;
        if (n >= M) continue;
        if (POOL == 0) {
            alignas(8) bf16 v[4];
#pragma unroll
            for (int j = 0; j < 4; ++j) {
                int o = o0 + tx * 4 + j;
                float s = acc[i][j] + bias[o];
                if (ACT == 0) s = (s >= 0.f) ? s : 0.01f * s;
                else          s = fmaxf(s, 0.f);
                v[j] = __float2bfloat16(s);
            }
            *(ushort4*)&out[(long long)n * Dout + o0 + tx * 4] = *(ushort4*)v;
        } else {
            int g = batch[n];
#pragma unroll
            for (int j = 0; j < 4; ++j) {
                int o = o0 + tx * 4 + j;
                float s = fmaxf(acc[i][j] + bias[o], 0.f);
                atomicAdd(&pooled[(long long)g * 512 + o], s);
            }
        }
    }
}

// ------------------------------------------------------------------
// graph boundaries via binary search on sorted batch
// ------------------------------------------------------------------
__global__ void bounds_kernel(const int* __restrict__ batch, int* __restrict__ gstart) {
    int g = blockIdx.x * blockDim.x + threadIdx.x;
    if (g > N_GRAPHS) return;
    int lo = 0, hi = N_NODES;
    while (lo < hi) {
        int mid = (lo + hi) >> 1;
        if (batch[mid] < g) lo = mid + 1;
        else hi = mid;
    }
    gstart[g] = lo;
}

__global__ void pool_finalize(float* __restrict__ pooled, const int* __restrict__ gstart) {
    int g = blockIdx.x;
    int f = threadIdx.x;
    float cnt = fmaxf((float)(gstart[g + 1] - gstart[g]), 1.0f);
    pooled[(long long)g * 512 + f] /= cnt;
}

// ------------------------------------------------------------------
// small dense: out[m][o] = act(in[m] . w[o] + b[o])
// ------------------------------------------------------------------
template <int ACT>  // 0 = none, 1 = relu
__global__ void mlp_kernel(const float* __restrict__ in, const float* __restrict__ w,
                           const float* __restrict__ b, float* __restrict__ out,
                           int M, int K, int O) {
    int t = blockIdx.x * blockDim.x + threadIdx.x;
    if (t >= M * O) return;
    int m = t / O, o = t % O;
    const float* ip = in + (long long)m * K;
    const float* wp = w + (long long)o * K;
    float s = 0.f;
    for (int k = 0; k < K; ++k) s += ip[k] * wp[k];
    s += b[o];
    if (ACT) s = fmaxf(s, 0.f);
    out[(long long)m * O + o] = s;
}

// ------------------------------------------------------------------
extern "C" void kernel_launch(void* const* d_in, const int* in_sizes, int n_in,
                              void* d_out, int out_size, void* d_ws, size_t ws_size,
                              hipStream_t stream) {
    const float* x     = (const float*)d_in[0];
    const int*   ei    = (const int*)d_in[1];
    const int*   batch = (const int*)d_in[2];
    const float* w1l = (const float*)d_in[3];
    const float* b1  = (const float*)d_in[4];
    const float* w1r = (const float*)d_in[5];
    const float* w2l = (const float*)d_in[6];
    const float* b2  = (const float*)d_in[7];
    const float* w2r = (const float*)d_in[8];
    const float* w3l = (const float*)d_in[9];
    const float* b3  = (const float*)d_in[10];
    const float* w3r = (const float*)d_in[11];
    const float* fc1_w = (const float*)d_in[12];
    const float* fc1_b = (const float*)d_in[13];
    const float* fc2_w = (const float*)d_in[14];
    const float* fc2_b = (const float*)d_in[15];
    const float* cls_w = (const float*)d_in[16];
    const float* cls_b = (const float*)d_in[17];
    float* out = (float*)d_out;

    const int* src = ei;
    const int* dst = ei + N_EDGES;

    // ---- workspace layout ----
    char* w = (char*)d_ws;
    size_t used = 0;
    auto alloc = [&](size_t bytes) {
        char* p = w + used;
        used += (bytes + 255) & ~(size_t)255;
        return p;
    };
    int*   cnt    = (int*)alloc((size_t)N_NODES * 4);           // also cursor
    int*   rowptr = (int*)alloc((size_t)(N_NODES + 1) * 4);
    int*   cols   = (int*)alloc((size_t)N_EDGES * 4);
    float* invdeg = (float*)alloc((size_t)N_NODES * 4);
    int*   gstart = (int*)alloc((size_t)(N_GRAPHS + 1) * 4);
    bf16*  AG     = (bf16*)alloc((size_t)N_NODES * 256 * 2);    // reused per layer
    bf16*  h1     = (bf16*)alloc((size_t)N_NODES * 128 * 2);
    bf16*  h2     = (bf16*)alloc((size_t)N_NODES * 256 * 2);
    float* pooled = (float*)alloc((size_t)N_GRAPHS * 512 * 4);
    float* z1     = (float*)alloc((size_t)N_GRAPHS * 256 * 4);
    float* z2     = (float*)alloc((size_t)N_GRAPHS * 128 * 4);

    // diagnostic guard: if workspace is too small, do nothing (clean absmax
    // fail instead of a GPU memory fault)
    if (ws_size < used) return;

    // ---- CSR build ----
    hipMemsetAsync(cnt, 0, (size_t)N_NODES * 4, stream);
    hist_kernel<<<(N_EDGES + 255) / 256, 256, 0, stream>>>(dst, cnt);
    scan_kernel<<<1, 1024, 0, stream>>>(cnt, rowptr);
    invdeg_kernel<<<(N_NODES + 255) / 256, 256, 0, stream>>>(rowptr, invdeg);
    copycur_kernel<<<(N_NODES + 255) / 256, 256, 0, stream>>>(rowptr, cnt);
    place_kernel<<<(N_EDGES + 255) / 256, 256, 0, stream>>>(src, dst, cnt, cols);
    bounds_kernel<<<2, 160, 0, stream>>>(batch, gstart);

    const int MB = (N_NODES + 63) / 64;  // 1563 row blocks

    // ---- layer 1: 50 -> 128, leaky_relu ----
    agg_kernel<float, 50><<<N_NODES, 64, 0, stream>>>(x, rowptr, cols, invdeg, AG);
    sage_gemm<bf16, float, 0, 0><<<dim3(2, MB), 256, 0, stream>>>(
        AG, x, w1l, w1r, b1, h1, nullptr, nullptr, N_NODES, 50, 128);

    // ---- layer 2: 128 -> 256, relu ----
    agg_kernel<bf16, 128><<<N_NODES, 128, 0, stream>>>(h1, rowptr, cols, invdeg, AG);
    sage_gemm<bf16, bf16, 1, 0><<<dim3(4, MB), 256, 0, stream>>>(
        AG, h1, w2l, w2r, b2, h2, nullptr, nullptr, N_NODES, 128, 256);

    // ---- layer 3: 256 -> 512, relu, fused global-mean-pool ----
    agg_kernel<bf16, 256><<<N_NODES, 256, 0, stream>>>(h2, rowptr, cols, invdeg, AG);
    hipMemsetAsync(pooled, 0, (size_t)N_GRAPHS * 512 * 4, stream);
    sage_gemm<bf16, bf16, 1, 1><<<dim3(8, MB), 256, 0, stream>>>(
        AG, h2, w3l, w3r, b3, nullptr, batch, pooled, N_NODES, 256, 512);
    pool_finalize<<<N_GRAPHS, 512, 0, stream>>>(pooled, gstart);

    // ---- MLP head ----
    mlp_kernel<1><<<(N_GRAPHS * 256 + 255) / 256, 256, 0, stream>>>(
        pooled, fc1_w, fc1_b, z1, N_GRAPHS, 512, 256);
    mlp_kernel<1><<<(N_GRAPHS * 128 + 255) / 256, 256, 0, stream>>>(
        z1, fc2_w, fc2_b, z2, N_GRAPHS, 256, 128);
    mlp_kernel<0><<<(N_GRAPHS * 15 + 255) / 256, 256, 0, stream>>>(
        z2, cls_w, cls_b, out, N_GRAPHS, 128, 15);
}

// Round 3
// 1388.142 us; speedup vs baseline: 3.8420x; 3.8420x over previous
//
#include <hip/hip_runtime.h>
#include <hip/hip_bf16.h>

#define N_NODES 100000
#define N_EDGES 3200000
#define N_GRAPHS 256

typedef __hip_bfloat16 bf16;
using f32x4  = __attribute__((ext_vector_type(4))) float;
using short8 = __attribute__((ext_vector_type(8))) short;

// ------------------------------------------------------------------
// CSR build: histogram -> exclusive scan -> placement
// ------------------------------------------------------------------
__global__ void hist_kernel(const int* __restrict__ dst, int* __restrict__ cnt) {
    int i = blockIdx.x * blockDim.x + threadIdx.x;
    if (i < N_EDGES) atomicAdd(&cnt[dst[i]], 1);
}

__global__ __launch_bounds__(1024) void scan_kernel(const int* __restrict__ cnt,
                                                    int* __restrict__ rowptr) {
    __shared__ int buf[1024];
    __shared__ int carry;
    if (threadIdx.x == 0) carry = 0;
    __syncthreads();
    for (int base = 0; base < N_NODES; base += 1024) {
        int i = base + threadIdx.x;
        int v = (i < N_NODES) ? cnt[i] : 0;
        buf[threadIdx.x] = v;
        __syncthreads();
        for (int off = 1; off < 1024; off <<= 1) {
            int t = (threadIdx.x >= off) ? buf[threadIdx.x - off] : 0;
            __syncthreads();
            buf[threadIdx.x] += t;
            __syncthreads();
        }
        int excl = carry + buf[threadIdx.x] - v;
        if (i < N_NODES) rowptr[i] = excl;
        __syncthreads();
        if (threadIdx.x == 0) carry += buf[1023];
        __syncthreads();
    }
    if (threadIdx.x == 0) rowptr[N_NODES] = carry;
}

__global__ void invdeg_kernel(const int* __restrict__ rowptr, float* __restrict__ invdeg) {
    int n = blockIdx.x * blockDim.x + threadIdx.x;
    if (n < N_NODES) {
        int d = rowptr[n + 1] - rowptr[n];
        invdeg[n] = 1.0f / fmaxf((float)d, 1.0f);
    }
}

__global__ void copycur_kernel(const int* __restrict__ rowptr, int* __restrict__ cursor) {
    int n = blockIdx.x * blockDim.x + threadIdx.x;
    if (n < N_NODES) cursor[n] = rowptr[n];
}

__global__ void place_kernel(const int* __restrict__ src, const int* __restrict__ dst,
                             int* __restrict__ cursor, int* __restrict__ cols) {
    int e = blockIdx.x * blockDim.x + threadIdx.x;
    if (e < N_EDGES) {
        int p = atomicAdd(&cursor[dst[e]], 1);
        cols[p] = src[e];
    }
}

// ------------------------------------------------------------------
// weight prep: fp32 [Dout][Din] -> bf16 [Dout][Kp] zero-padded
// ------------------------------------------------------------------
__global__ void wprep_kernel(const float* __restrict__ w, bf16* __restrict__ out,
                             int Dout, int Din, int Kp) {
    int t = blockIdx.x * blockDim.x + threadIdx.x;
    if (t >= Dout * Kp) return;
    int o = t / Kp, k = t % Kp;
    out[t] = __float2bfloat16(k < Din ? w[(long long)o * Din + k] : 0.f);
}

// ------------------------------------------------------------------
// layer-1 aggregation (fp32 x, D=50), writes agg zero-padded to width 64
// ------------------------------------------------------------------
__global__ void agg1_kernel(const float* __restrict__ x, const int* __restrict__ rowptr,
                            const int* __restrict__ cols, const float* __restrict__ invdeg,
                            bf16* __restrict__ AG1) {
    int n = blockIdx.x, f = threadIdx.x;  // 64 threads
    int s = rowptr[n], e = rowptr[n + 1];
    float sum = 0.f;
    if (f < 50) {
        for (int j = s; j < e; ++j) sum += x[(size_t)cols[j] * 50 + f];
        sum *= invdeg[n];
    }
    AG1[(size_t)n * 64 + f] = __float2bfloat16(f < 50 ? sum : 0.f);
}

// ------------------------------------------------------------------
// vectorized gather aggregation (bf16, D = 128 or 256)
// ------------------------------------------------------------------
template <int D>
__global__ void aggv_kernel(const bf16* __restrict__ h, const int* __restrict__ rowptr,
                            const int* __restrict__ cols, const float* __restrict__ invdeg,
                            bf16* __restrict__ AG) {
    constexpr int L = D / 8;            // lanes per node
    int n = blockIdx.x * (256 / L) + threadIdx.x / L;
    int lane = threadIdx.x % L;
    if (n >= N_NODES) return;
    int s = rowptr[n], e = rowptr[n + 1];
    float acc[8] = {};
    for (int j = s; j < e; ++j) {
        int c = cols[j];
        uint4 v = *(const uint4*)&h[(size_t)c * D + lane * 8];
        const unsigned short* u = (const unsigned short*)&v;
#pragma unroll
        for (int i = 0; i < 8; ++i) {
            union { unsigned int ui; float f; } cv;
            cv.ui = ((unsigned int)u[i]) << 16;
            acc[i] += cv.f;
        }
    }
    float inv = invdeg[n];
    union { uint4 u; bf16 h8[8]; } o;
#pragma unroll
    for (int i = 0; i < 8; ++i) o.h8[i] = __float2bfloat16(acc[i] * inv);
    *(uint4*)&AG[(size_t)n * D + lane * 8] = o.u;
}

// ------------------------------------------------------------------
// MFMA GEMM: C[M][Dout] = act( [A1|A2] @ [B1|B2]^T + bias )
// A1: bf16 [M][ldA1] (K1 cols), A2: bf16 or fp32 [M][ldA2] (K2 cols, guard maxc2)
// B1: bf16 [Dout][K1], B2: bf16 [Dout][K2]
// 128x128 tile, BK=32, 256 threads = 4 waves (2x2), 16x16x32 MFMA
// POOL=1: fused relu + segmented graph pooling (atomicAdd into pooled)
// ------------------------------------------------------------------
__device__ __forceinline__ uint4 pack8(const float* t) {
    union { uint4 u; bf16 h[8]; } r;
#pragma unroll
    for (int i = 0; i < 8; ++i) r.h[i] = __float2bfloat16(t[i]);
    return r.u;
}

template <int A2F, int ACT, int POOL>
__global__ __launch_bounds__(256) void mfma_gemm(
        const bf16* __restrict__ A1, int ldA1, int K1,
        const void* __restrict__ A2v, int ldA2, int K2, int maxc2,
        const bf16* __restrict__ B1, const bf16* __restrict__ B2,
        const float* __restrict__ bias, bf16* __restrict__ out,
        int M, int Dout,
        const int* __restrict__ batch, float* __restrict__ pooled) {
    __shared__ bf16 As[128][40];   // +8 pad: 80B row stride -> conflict-free b128
    __shared__ bf16 Bs[128][40];
    __shared__ int sbatch[128];

    const int tid = threadIdx.x;
    const int n0 = blockIdx.y * 128;
    const int o0 = blockIdx.x * 128;

    if (POOL && tid < 128) {
        int n = n0 + tid;
        sbatch[tid] = (n < M) ? batch[n] : -1;
    }

    const int lane = tid & 63;
    const int w = tid >> 6;
    const int wr = w >> 1, wc = w & 1;
    const int lr = lane & 15, hi = lane >> 4;

    f32x4 acc[4][4] = {};

    const int r = tid >> 2;          // 0..63 (staging row)
    const int kc = (tid & 3) * 8;    // 0,8,16,24 (staging k-chunk)
    const int KT = K1 + K2;

    for (int k0 = 0; k0 < KT; k0 += 32) {
        uint4 a0 = {0, 0, 0, 0}, a1 = {0, 0, 0, 0};
        uint4 b0, b1;
        // ---- A tile global loads (guarded) ----
        {
            int ra = n0 + r, rb = ra + 64;
            if (k0 < K1) {
                int c = k0 + kc;
                if (ra < M) a0 = *(const uint4*)&A1[(size_t)ra * ldA1 + c];
                if (rb < M) a1 = *(const uint4*)&A1[(size_t)rb * ldA1 + c];
            } else if (A2F) {
                const float* A2 = (const float*)A2v;
                int c = k0 - K1 + kc;
                float t0[8], t1[8];
#pragma unroll
                for (int i = 0; i < 8; ++i) {
                    int cc = c + i;
                    bool cok = (cc < maxc2);
                    t0[i] = (cok && ra < M) ? A2[(size_t)ra * ldA2 + cc] : 0.f;
                    t1[i] = (cok && rb < M) ? A2[(size_t)rb * ldA2 + cc] : 0.f;
                }
                a0 = pack8(t0);
                a1 = pack8(t1);
            } else {
                const bf16* A2 = (const bf16*)A2v;
                int c = k0 - K1 + kc;
                if (ra < M) a0 = *(const uint4*)&A2[(size_t)ra * ldA2 + c];
                if (rb < M) a1 = *(const uint4*)&A2[(size_t)rb * ldA2 + c];
            }
        }
        // ---- B tile global loads (Dout rows always valid) ----
        {
            const bf16* Bsrc;
            int ldb, c;
            if (k0 < K1) { Bsrc = B1; ldb = K1; c = k0 + kc; }
            else         { Bsrc = B2; ldb = K2; c = k0 - K1 + kc; }
            int oa = o0 + r;
            b0 = *(const uint4*)&Bsrc[(size_t)oa * ldb + c];
            b1 = *(const uint4*)&Bsrc[(size_t)(oa + 64) * ldb + c];
        }
        __syncthreads();   // previous iteration done reading LDS
        *(uint4*)&As[r][kc] = a0;
        *(uint4*)&As[r + 64][kc] = a1;
        *(uint4*)&Bs[r][kc] = b0;
        *(uint4*)&Bs[r + 64][kc] = b1;
        __syncthreads();

        short8 af[4], bfr[4];
#pragma unroll
        for (int m = 0; m < 4; ++m)
            af[m] = *(const short8*)&As[wr * 64 + m * 16 + lr][hi * 8];
#pragma unroll
        for (int n = 0; n < 4; ++n)
            bfr[n] = *(const short8*)&Bs[wc * 64 + n * 16 + lr][hi * 8];
#pragma unroll
        for (int m = 0; m < 4; ++m)
#pragma unroll
            for (int n = 0; n < 4; ++n)
                acc[m][n] = __builtin_amdgcn_mfma_f32_16x16x32_bf16(af[m], bfr[n], acc[m][n], 0, 0, 0);
    }

    float bias_v[4];
#pragma unroll
    for (int n = 0; n < 4; ++n) bias_v[n] = bias[o0 + wc * 64 + n * 16 + lr];

    if (!POOL) {
#pragma unroll
        for (int m = 0; m < 4; ++m) {
#pragma unroll
            for (int j = 0; j < 4; ++j) {
                int row = n0 + wr * 64 + m * 16 + hi * 4 + j;
                if (row < M) {
#pragma unroll
                    for (int n = 0; n < 4; ++n) {
                        float s = acc[m][n][j] + bias_v[n];
                        if (ACT == 0) s = (s >= 0.f) ? s : 0.01f * s;
                        else          s = fmaxf(s, 0.f);
                        out[(size_t)row * Dout + o0 + wc * 64 + n * 16 + lr] = __float2bfloat16(s);
                    }
                }
            }
        }
    } else {
        // segmented pooled reduction: batch is sorted, block spans few graphs
        int lastv = min(127, M - 1 - n0);
        int gmin = sbatch[0], gmax = sbatch[lastv];
        for (int g = gmin; g <= gmax; ++g) {
            float s[4] = {0.f, 0.f, 0.f, 0.f};
#pragma unroll
            for (int m = 0; m < 4; ++m) {
#pragma unroll
                for (int j = 0; j < 4; ++j) {
                    int rl = wr * 64 + m * 16 + hi * 4 + j;
                    if (sbatch[rl] == g) {
#pragma unroll
                        for (int n = 0; n < 4; ++n)
                            s[n] += fmaxf(acc[m][n][j] + bias_v[n], 0.f);
                    }
                }
            }
#pragma unroll
            for (int n = 0; n < 4; ++n) {
                float v = s[n];
                v += __shfl_xor(v, 16, 64);
                v += __shfl_xor(v, 32, 64);
                if (hi == 0)
                    atomicAdd(&pooled[(size_t)g * 512 + o0 + wc * 64 + n * 16 + lr], v);
            }
        }
    }
}

// ------------------------------------------------------------------
// graph boundaries + pool finalize
// ------------------------------------------------------------------
__global__ void bounds_kernel(const int* __restrict__ batch, int* __restrict__ gstart) {
    int g = blockIdx.x * blockDim.x + threadIdx.x;
    if (g > N_GRAPHS) return;
    int lo = 0, hi = N_NODES;
    while (lo < hi) {
        int mid = (lo + hi) >> 1;
        if (batch[mid] < g) lo = mid + 1;
        else hi = mid;
    }
    gstart[g] = lo;
}

__global__ void pool_finalize(float* __restrict__ pooled, const int* __restrict__ gstart) {
    int g = blockIdx.x;
    int f = threadIdx.x;
    float cnt = fmaxf((float)(gstart[g + 1] - gstart[g]), 1.0f);
    pooled[(size_t)g * 512 + f] /= cnt;
}

// ------------------------------------------------------------------
// small dense head
// ------------------------------------------------------------------
template <int ACT>  // 0 = none, 1 = relu
__global__ void mlp_kernel(const float* __restrict__ in, const float* __restrict__ w,
                           const float* __restrict__ b, float* __restrict__ out,
                           int M, int K, int O) {
    int t = blockIdx.x * blockDim.x + threadIdx.x;
    if (t >= M * O) return;
    int m = t / O, o = t % O;
    const float* ip = in + (size_t)m * K;
    const float* wp = w + (size_t)o * K;
    float s = 0.f;
    for (int k = 0; k < K; ++k) s += ip[k] * wp[k];
    s += b[o];
    if (ACT) s = fmaxf(s, 0.f);
    out[(size_t)m * O + o] = s;
}

// ------------------------------------------------------------------
extern "C" void kernel_launch(void* const* d_in, const int* in_sizes, int n_in,
                              void* d_out, int out_size, void* d_ws, size_t ws_size,
                              hipStream_t stream) {
    const float* x     = (const float*)d_in[0];
    const int*   ei    = (const int*)d_in[1];
    const int*   batch = (const int*)d_in[2];
    const float* w1l = (const float*)d_in[3];
    const float* b1  = (const float*)d_in[4];
    const float* w1r = (const float*)d_in[5];
    const float* w2l = (const float*)d_in[6];
    const float* b2  = (const float*)d_in[7];
    const float* w2r = (const float*)d_in[8];
    const float* w3l = (const float*)d_in[9];
    const float* b3  = (const float*)d_in[10];
    const float* w3r = (const float*)d_in[11];
    const float* fc1_w = (const float*)d_in[12];
    const float* fc1_b = (const float*)d_in[13];
    const float* fc2_w = (const float*)d_in[14];
    const float* fc2_b = (const float*)d_in[15];
    const float* cls_w = (const float*)d_in[16];
    const float* cls_b = (const float*)d_in[17];
    float* out = (float*)d_out;

    const int* src = ei;
    const int* dst = ei + N_EDGES;

    // ---- workspace layout ----
    char* wsp = (char*)d_ws;
    size_t used = 0;
    auto alloc = [&](size_t bytes) {
        char* p = wsp + used;
        used += (bytes + 255) & ~(size_t)255;
        return p;
    };
    int*   cnt    = (int*)alloc((size_t)N_NODES * 4);
    int*   rowptr = (int*)alloc((size_t)(N_NODES + 1) * 4);
    int*   cols   = (int*)alloc((size_t)N_EDGES * 4);
    float* invdeg = (float*)alloc((size_t)N_NODES * 4);
    int*   gstart = (int*)alloc((size_t)(N_GRAPHS + 1) * 4);
    // overlay region R (51.2 MB): AG1/AG2/AG3 at base, h1 at +25.6MB
    char*  R      = alloc((size_t)N_NODES * 256 * 2);
    bf16*  AG     = (bf16*)R;                                   // layer aggs
    bf16*  h1     = (bf16*)(R + (size_t)N_NODES * 128 * 2);     // dead after gemm2
    bf16*  h2     = (bf16*)alloc((size_t)N_NODES * 256 * 2);
    bf16*  w1l_b  = (bf16*)alloc(128 * 64 * 2);
    bf16*  w1r_b  = (bf16*)alloc(128 * 64 * 2);
    bf16*  w2l_b  = (bf16*)alloc(256 * 128 * 2);
    bf16*  w2r_b  = (bf16*)alloc(256 * 128 * 2);
    bf16*  w3l_b  = (bf16*)alloc(512 * 256 * 2);
    bf16*  w3r_b  = (bf16*)alloc(512 * 256 * 2);
    float* pooled = (float*)alloc((size_t)N_GRAPHS * 512 * 4);
    float* z1     = (float*)alloc((size_t)N_GRAPHS * 256 * 4);
    float* z2     = (float*)alloc((size_t)N_GRAPHS * 128 * 4);

    if (ws_size < used) return;  // clean fail instead of fault

    // ---- CSR build ----
    hipMemsetAsync(cnt, 0, (size_t)N_NODES * 4, stream);
    hist_kernel<<<(N_EDGES + 255) / 256, 256, 0, stream>>>(dst, cnt);
    scan_kernel<<<1, 1024, 0, stream>>>(cnt, rowptr);
    invdeg_kernel<<<(N_NODES + 255) / 256, 256, 0, stream>>>(rowptr, invdeg);
    copycur_kernel<<<(N_NODES + 255) / 256, 256, 0, stream>>>(rowptr, cnt);
    place_kernel<<<(N_EDGES + 255) / 256, 256, 0, stream>>>(src, dst, cnt, cols);
    bounds_kernel<<<2, 160, 0, stream>>>(batch, gstart);

    // ---- weight prep (bf16, K zero-padded) ----
    wprep_kernel<<<(128 * 64 + 255) / 256, 256, 0, stream>>>(w1l, w1l_b, 128, 50, 64);
    wprep_kernel<<<(128 * 64 + 255) / 256, 256, 0, stream>>>(w1r, w1r_b, 128, 50, 64);
    wprep_kernel<<<(256 * 128 + 255) / 256, 256, 0, stream>>>(w2l, w2l_b, 256, 128, 128);
    wprep_kernel<<<(256 * 128 + 255) / 256, 256, 0, stream>>>(w2r, w2r_b, 256, 128, 128);
    wprep_kernel<<<(512 * 256 + 255) / 256, 256, 0, stream>>>(w3l, w3l_b, 512, 256, 256);
    wprep_kernel<<<(512 * 256 + 255) / 256, 256, 0, stream>>>(w3r, w3r_b, 512, 256, 256);

    const int MB = (N_NODES + 127) / 128;  // 782 row blocks

    // ---- layer 1: 50 -> 128, leaky_relu ----
    agg1_kernel<<<N_NODES, 64, 0, stream>>>(x, rowptr, cols, invdeg, AG);
    mfma_gemm<1, 0, 0><<<dim3(1, MB), 256, 0, stream>>>(
        AG, 64, 64, x, 50, 64, 50, w1l_b, w1r_b, b1, h1, N_NODES, 128, nullptr, nullptr);

    // ---- layer 2: 128 -> 256, relu ----
    aggv_kernel<128><<<(N_NODES * 16 + 255) / 256, 256, 0, stream>>>(h1, rowptr, cols, invdeg, AG);
    mfma_gemm<0, 1, 0><<<dim3(2, MB), 256, 0, stream>>>(
        AG, 128, 128, h1, 128, 128, 128, w2l_b, w2r_b, b2, h2, N_NODES, 256, nullptr, nullptr);

    // ---- layer 3: 256 -> 512, relu, fused pooled sum ----
    aggv_kernel<256><<<(N_NODES * 32 + 255) / 256, 256, 0, stream>>>(h2, rowptr, cols, invdeg, AG);
    hipMemsetAsync(pooled, 0, (size_t)N_GRAPHS * 512 * 4, stream);
    mfma_gemm<0, 1, 1><<<dim3(4, MB), 256, 0, stream>>>(
        AG, 256, 256, h2, 256, 256, 256, w3l_b, w3r_b, b3, nullptr, N_NODES, 512, batch, pooled);
    pool_finalize<<<N_GRAPHS, 512, 0, stream>>>(pooled, gstart);

    // ---- MLP head ----
    mlp_kernel<1><<<(N_GRAPHS * 256 + 255) / 256, 256, 0, stream>>>(
        pooled, fc1_w, fc1_b, z1, N_GRAPHS, 512, 256);
    mlp_kernel<1><<<(N_GRAPHS * 128 + 255) / 256, 256, 0, stream>>>(
        z1, fc2_w, fc2_b, z2, N_GRAPHS, 256, 128);
    mlp_kernel<0><<<(N_GRAPHS * 15 + 255) / 256, 256, 0, stream>>>(
        z2, cls_w, cls_b, out, N_GRAPHS, 128, 15);
}

// Round 4
// 932.704 us; speedup vs baseline: 5.7180x; 1.4883x over previous
//
#include <hip/hip_runtime.h>
#include <hip/hip_bf16.h>

#define N_NODES 100000
#define N_EDGES 3200000
#define N_GRAPHS 256
#define SCAN_NB 98   // ceil(100000/1024)

typedef __hip_bfloat16 bf16;
using f32x4  = __attribute__((ext_vector_type(4))) float;
using short8 = __attribute__((ext_vector_type(8))) short;

// ------------------------------------------------------------------
// CSR build, single atomic pass:
//   rank[e] = old count of dst[e];  cnt -> degree
// ------------------------------------------------------------------
__global__ void rank_kernel(const int* __restrict__ dst, int* __restrict__ cnt,
                            unsigned short* __restrict__ rank) {
    int e = blockIdx.x * blockDim.x + threadIdx.x;
    if (e < N_EDGES) rank[e] = (unsigned short)atomicAdd(&cnt[dst[e]], 1);
}

// block-local exclusive scan (1024 elems/block) + block totals
__global__ __launch_bounds__(1024) void scan_blocks_kernel(const int* __restrict__ cnt,
                                                           int* __restrict__ excl,
                                                           int* __restrict__ partial) {
    __shared__ int buf[1024];
    int tid = threadIdx.x;
    int i = blockIdx.x * 1024 + tid;
    int v = (i < N_NODES) ? cnt[i] : 0;
    buf[tid] = v;
    __syncthreads();
    for (int off = 1; off < 1024; off <<= 1) {
        int t = (tid >= off) ? buf[tid - off] : 0;
        __syncthreads();
        buf[tid] += t;
        __syncthreads();
    }
    if (i < N_NODES) excl[i] = buf[tid] - v;
    if (tid == 1023) partial[blockIdx.x] = buf[1023];
}

// exclusive scan of SCAN_NB block totals (partial[SCAN_NB] = grand total)
__global__ __launch_bounds__(128) void scan_partial_kernel(int* __restrict__ partial) {
    __shared__ int sp[128];
    int tid = threadIdx.x;
    int v = (tid < SCAN_NB) ? partial[tid] : 0;
    sp[tid] = v;
    __syncthreads();
    for (int off = 1; off < 128; off <<= 1) {
        int t = (tid >= off) ? sp[tid - off] : 0;
        __syncthreads();
        sp[tid] += t;
        __syncthreads();
    }
    if (tid <= SCAN_NB) partial[tid] = sp[tid] - v;   // exclusive
}

// rowptr = excl + partial[block]; invdeg from cnt (degree)
__global__ void scan_add_kernel(const int* __restrict__ excl, const int* __restrict__ partial,
                                const int* __restrict__ cnt, int* __restrict__ rowptr,
                                float* __restrict__ invdeg) {
    int i = blockIdx.x * blockDim.x + threadIdx.x;
    if (i < N_NODES) {
        rowptr[i] = excl[i] + partial[i >> 10];
        invdeg[i] = 1.0f / fmaxf((float)cnt[i], 1.0f);
    } else if (i == N_NODES) {
        rowptr[N_NODES] = partial[SCAN_NB];
    }
}

// atomic-free placement
__global__ void place2_kernel(const int* __restrict__ src, const int* __restrict__ dst,
                              const unsigned short* __restrict__ rank,
                              const int* __restrict__ rowptr, int* __restrict__ cols) {
    int e = blockIdx.x * blockDim.x + threadIdx.x;
    if (e < N_EDGES) cols[rowptr[dst[e]] + (int)rank[e]] = src[e];
}

// ------------------------------------------------------------------
// weight prep: fp32 [Dout][Din] -> bf16 [Dout][Kp] zero-padded
// ------------------------------------------------------------------
__global__ void wprep_kernel(const float* __restrict__ w, bf16* __restrict__ out,
                             int Dout, int Din, int Kp) {
    int t = blockIdx.x * blockDim.x + threadIdx.x;
    if (t >= Dout * Kp) return;
    int o = t / Kp, k = t % Kp;
    out[t] = __float2bfloat16(k < Din ? w[(long long)o * Din + k] : 0.f);
}

// ------------------------------------------------------------------
// layer-1 aggregation (fp32 x, D=50), agg zero-padded to width 64
// ------------------------------------------------------------------
__global__ void agg1_kernel(const float* __restrict__ x, const int* __restrict__ rowptr,
                            const int* __restrict__ cols, const float* __restrict__ invdeg,
                            bf16* __restrict__ AG1) {
    int n = blockIdx.x, f = threadIdx.x;  // 64 threads
    int s = rowptr[n], e = rowptr[n + 1];
    float s0 = 0.f, s1 = 0.f;
    if (f < 50) {
        int j = s;
        for (; j + 2 <= e; j += 2) {
            int c0 = cols[j], c1 = cols[j + 1];
            s0 += x[(size_t)c0 * 50 + f];
            s1 += x[(size_t)c1 * 50 + f];
        }
        if (j < e) s0 += x[(size_t)cols[j] * 50 + f];
        s0 = (s0 + s1) * invdeg[n];
    }
    AG1[(size_t)n * 64 + f] = __float2bfloat16(f < 50 ? s0 : 0.f);
}

// ------------------------------------------------------------------
// vectorized gather aggregation (bf16, D = 128 or 256), 2-edge unroll
// ------------------------------------------------------------------
template <int D>
__global__ void aggv_kernel(const bf16* __restrict__ h, const int* __restrict__ rowptr,
                            const int* __restrict__ cols, const float* __restrict__ invdeg,
                            bf16* __restrict__ AG) {
    constexpr int L = D / 8;
    int n = blockIdx.x * (256 / L) + threadIdx.x / L;
    int lane = threadIdx.x % L;
    if (n >= N_NODES) return;
    int s = rowptr[n], e = rowptr[n + 1];
    float acc[8] = {};
    auto accum = [&](uint4 v) {
        const unsigned short* u = (const unsigned short*)&v;
#pragma unroll
        for (int i = 0; i < 8; ++i) {
            union { unsigned int ui; float f; } cv;
            cv.ui = ((unsigned int)u[i]) << 16;
            acc[i] += cv.f;
        }
    };
    int j = s;
    for (; j + 2 <= e; j += 2) {
        int c0 = cols[j], c1 = cols[j + 1];
        uint4 v0 = *(const uint4*)&h[(size_t)c0 * D + lane * 8];
        uint4 v1 = *(const uint4*)&h[(size_t)c1 * D + lane * 8];
        accum(v0);
        accum(v1);
    }
    if (j < e) accum(*(const uint4*)&h[(size_t)cols[j] * D + lane * 8]);
    float inv = invdeg[n];
    union { uint4 u; bf16 h8[8]; } o;
#pragma unroll
    for (int i = 0; i < 8; ++i) o.h8[i] = __float2bfloat16(acc[i] * inv);
    *(uint4*)&AG[(size_t)n * D + lane * 8] = o.u;
}

// ------------------------------------------------------------------
// layer-1 MFMA GEMM (reg-staged; handles fp32 A2): kept from round 3
// ------------------------------------------------------------------
__device__ __forceinline__ uint4 pack8(const float* t) {
    union { uint4 u; bf16 h[8]; } r;
#pragma unroll
    for (int i = 0; i < 8; ++i) r.h[i] = __float2bfloat16(t[i]);
    return r.u;
}

__global__ __launch_bounds__(256) void mfma_gemm1(
        const bf16* __restrict__ A1, int ldA1, int K1,
        const float* __restrict__ A2, int ldA2, int K2, int maxc2,
        const bf16* __restrict__ B1, const bf16* __restrict__ B2,
        const float* __restrict__ bias, bf16* __restrict__ out,
        int M, int Dout) {
    __shared__ bf16 As[128][40];
    __shared__ bf16 Bs[128][40];

    const int tid = threadIdx.x;
    const int n0 = blockIdx.y * 128;
    const int o0 = blockIdx.x * 128;
    const int lane = tid & 63;
    const int w = tid >> 6;
    const int wr = w >> 1, wc = w & 1;
    const int lr = lane & 15, hi = lane >> 4;

    f32x4 acc[4][4] = {};
    const int r = tid >> 2;
    const int kc = (tid & 3) * 8;
    const int KT = K1 + K2;

    for (int k0 = 0; k0 < KT; k0 += 32) {
        uint4 a0 = {0, 0, 0, 0}, a1 = {0, 0, 0, 0};
        uint4 b0, b1;
        {
            int ra = n0 + r, rb = ra + 64;
            if (k0 < K1) {
                int c = k0 + kc;
                if (ra < M) a0 = *(const uint4*)&A1[(size_t)ra * ldA1 + c];
                if (rb < M) a1 = *(const uint4*)&A1[(size_t)rb * ldA1 + c];
            } else {
                int c = k0 - K1 + kc;
                float t0[8], t1[8];
#pragma unroll
                for (int i = 0; i < 8; ++i) {
                    int cc = c + i;
                    bool cok = (cc < maxc2);
                    t0[i] = (cok && ra < M) ? A2[(size_t)ra * ldA2 + cc] : 0.f;
                    t1[i] = (cok && rb < M) ? A2[(size_t)rb * ldA2 + cc] : 0.f;
                }
                a0 = pack8(t0);
                a1 = pack8(t1);
            }
        }
        {
            const bf16* Bsrc;
            int ldb, c;
            if (k0 < K1) { Bsrc = B1; ldb = K1; c = k0 + kc; }
            else         { Bsrc = B2; ldb = K2; c = k0 - K1 + kc; }
            int oa = o0 + r;
            b0 = *(const uint4*)&Bsrc[(size_t)oa * ldb + c];
            b1 = *(const uint4*)&Bsrc[(size_t)(oa + 64) * ldb + c];
        }
        __syncthreads();
        *(uint4*)&As[r][kc] = a0;
        *(uint4*)&As[r + 64][kc] = a1;
        *(uint4*)&Bs[r][kc] = b0;
        *(uint4*)&Bs[r + 64][kc] = b1;
        __syncthreads();

        short8 af[4], bfr[4];
#pragma unroll
        for (int m = 0; m < 4; ++m)
            af[m] = *(const short8*)&As[wr * 64 + m * 16 + lr][hi * 8];
#pragma unroll
        for (int n = 0; n < 4; ++n)
            bfr[n] = *(const short8*)&Bs[wc * 64 + n * 16 + lr][hi * 8];
#pragma unroll
        for (int m = 0; m < 4; ++m)
#pragma unroll
            for (int n = 0; n < 4; ++n)
                acc[m][n] = __builtin_amdgcn_mfma_f32_16x16x32_bf16(af[m], bfr[n], acc[m][n], 0, 0, 0);
    }

    float bias_v[4];
#pragma unroll
    for (int n = 0; n < 4; ++n) bias_v[n] = bias[o0 + wc * 64 + n * 16 + lr];

#pragma unroll
    for (int m = 0; m < 4; ++m) {
#pragma unroll
        for (int j = 0; j < 4; ++j) {
            int row = n0 + wr * 64 + m * 16 + hi * 4 + j;
            if (row < M) {
#pragma unroll
                for (int n = 0; n < 4; ++n) {
                    float s = acc[m][n][j] + bias_v[n];
                    s = (s >= 0.f) ? s : 0.01f * s;   // leaky_relu
                    out[(size_t)row * Dout + o0 + wc * 64 + n * 16 + lr] = __float2bfloat16(s);
                }
            }
        }
    }
}

// ------------------------------------------------------------------
// m97-style MFMA GEMM (layers 2/3): global_load_lds(16B), linear LDS,
// 2-barrier loop. A = [A1|A2] bf16, ld == Kh for all operands.
// POOL=1: fused relu + segmented graph pooling.
// ------------------------------------------------------------------
template <int POOL>
__global__ __launch_bounds__(256) void glds_gemm(
        const bf16* __restrict__ A1, const bf16* __restrict__ A2, int Kh,
        const bf16* __restrict__ B1, const bf16* __restrict__ B2,
        const float* __restrict__ bias, bf16* __restrict__ out,
        int M, int Dout,
        const int* __restrict__ batch, float* __restrict__ pooled) {
    __shared__ alignas(16) bf16 As[128][32];
    __shared__ alignas(16) bf16 Bs[128][32];
    __shared__ int sbatch[128];

    const int tid = threadIdx.x;
    const int n0 = blockIdx.y * 128;
    const int o0 = blockIdx.x * 128;

    if (POOL && tid < 128) {
        int n = n0 + tid;
        sbatch[tid] = (n < M) ? batch[n] : -1;
    }

    const int lane = tid & 63;
    const int w = tid >> 6;
    const int wr = w >> 1, wc = w & 1;
    const int lr = lane & 15, hi = lane >> 4;
    const int l4 = lane >> 2;          // 0..15: row within 16-row chunk
    const int kc8 = (lane & 3) * 8;    // 0,8,16,24

    f32x4 acc[4][4] = {};

    const int KT = 2 * Kh;
    for (int k0 = 0; k0 < KT; k0 += 32) {
        const bf16* Ap;
        const bf16* Bp;
        int kk;
        if (k0 < Kh) { Ap = A1; Bp = B1; kk = k0; }
        else         { Ap = A2; Bp = B2; kk = k0 - Kh; }
#pragma unroll
        for (int c = 0; c < 2; ++c) {
            int rl = w * 32 + c * 16 + l4;  // tile row 0..127
            // A: clamp row (invalid rows feed only dead outputs)
            size_t ga = (size_t)min(n0 + rl, M - 1) * (size_t)Kh + kk + kc8;
            __builtin_amdgcn_global_load_lds(
                (const __attribute__((address_space(1))) void*)(Ap + ga),
                (__attribute__((address_space(3))) void*)&As[w * 32 + c * 16][0], 16, 0, 0);
            // B: all Dout rows valid
            size_t gb = (size_t)(o0 + rl) * (size_t)Kh + kk + kc8;
            __builtin_amdgcn_global_load_lds(
                (const __attribute__((address_space(1))) void*)(Bp + gb),
                (__attribute__((address_space(3))) void*)&Bs[w * 32 + c * 16][0], 16, 0, 0);
        }
        __syncthreads();   // drains vmcnt(0): DMA landed

        short8 af[4], bfr[4];
#pragma unroll
        for (int m = 0; m < 4; ++m)
            af[m] = *(const short8*)&As[wr * 64 + m * 16 + lr][hi * 8];
#pragma unroll
        for (int n = 0; n < 4; ++n)
            bfr[n] = *(const short8*)&Bs[wc * 64 + n * 16 + lr][hi * 8];
#pragma unroll
        for (int m = 0; m < 4; ++m)
#pragma unroll
            for (int n = 0; n < 4; ++n)
                acc[m][n] = __builtin_amdgcn_mfma_f32_16x16x32_bf16(af[m], bfr[n], acc[m][n], 0, 0, 0);
        __syncthreads();   // all waves done reading before next DMA overwrites
    }

    float bias_v[4];
#pragma unroll
    for (int n = 0; n < 4; ++n) bias_v[n] = bias[o0 + wc * 64 + n * 16 + lr];

    if (!POOL) {
#pragma unroll
        for (int m = 0; m < 4; ++m) {
#pragma unroll
            for (int j = 0; j < 4; ++j) {
                int row = n0 + wr * 64 + m * 16 + hi * 4 + j;
                if (row < M) {
#pragma unroll
                    for (int n = 0; n < 4; ++n) {
                        float s = fmaxf(acc[m][n][j] + bias_v[n], 0.f);
                        out[(size_t)row * Dout + o0 + wc * 64 + n * 16 + lr] = __float2bfloat16(s);
                    }
                }
            }
        }
    } else {
        int lastv = min(127, M - 1 - n0);
        int gmin = sbatch[0], gmax = sbatch[lastv];
        for (int g = gmin; g <= gmax; ++g) {
            float s[4] = {0.f, 0.f, 0.f, 0.f};
#pragma unroll
            for (int m = 0; m < 4; ++m) {
#pragma unroll
                for (int j = 0; j < 4; ++j) {
                    int rl = wr * 64 + m * 16 + hi * 4 + j;
                    if (sbatch[rl] == g) {
#pragma unroll
                        for (int n = 0; n < 4; ++n)
                            s[n] += fmaxf(acc[m][n][j] + bias_v[n], 0.f);
                    }
                }
            }
#pragma unroll
            for (int n = 0; n < 4; ++n) {
                float v = s[n];
                v += __shfl_xor(v, 16, 64);
                v += __shfl_xor(v, 32, 64);
                if (hi == 0)
                    atomicAdd(&pooled[(size_t)g * 512 + o0 + wc * 64 + n * 16 + lr], v);
            }
        }
    }
}

// ------------------------------------------------------------------
// graph boundaries + pool finalize + MLP head
// ------------------------------------------------------------------
__global__ void bounds_kernel(const int* __restrict__ batch, int* __restrict__ gstart) {
    int g = blockIdx.x * blockDim.x + threadIdx.x;
    if (g > N_GRAPHS) return;
    int lo = 0, hi = N_NODES;
    while (lo < hi) {
        int mid = (lo + hi) >> 1;
        if (batch[mid] < g) lo = mid + 1;
        else hi = mid;
    }
    gstart[g] = lo;
}

__global__ void pool_finalize(float* __restrict__ pooled, const int* __restrict__ gstart) {
    int g = blockIdx.x;
    int f = threadIdx.x;
    float cnt = fmaxf((float)(gstart[g + 1] - gstart[g]), 1.0f);
    pooled[(size_t)g * 512 + f] /= cnt;
}

template <int ACT>  // 0 = none, 1 = relu
__global__ void mlp_kernel(const float* __restrict__ in, const float* __restrict__ w,
                           const float* __restrict__ b, float* __restrict__ out,
                           int M, int K, int O) {
    int t = blockIdx.x * blockDim.x + threadIdx.x;
    if (t >= M * O) return;
    int m = t / O, o = t % O;
    const float* ip = in + (size_t)m * K;
    const float* wp = w + (size_t)o * K;
    float s = 0.f;
    for (int k = 0; k < K; ++k) s += ip[k] * wp[k];
    s += b[o];
    if (ACT) s = fmaxf(s, 0.f);
    out[(size_t)m * O + o] = s;
}

// ------------------------------------------------------------------
extern "C" void kernel_launch(void* const* d_in, const int* in_sizes, int n_in,
                              void* d_out, int out_size, void* d_ws, size_t ws_size,
                              hipStream_t stream) {
    const float* x     = (const float*)d_in[0];
    const int*   ei    = (const int*)d_in[1];
    const int*   batch = (const int*)d_in[2];
    const float* w1l = (const float*)d_in[3];
    const float* b1  = (const float*)d_in[4];
    const float* w1r = (const float*)d_in[5];
    const float* w2l = (const float*)d_in[6];
    const float* b2  = (const float*)d_in[7];
    const float* w2r = (const float*)d_in[8];
    const float* w3l = (const float*)d_in[9];
    const float* b3  = (const float*)d_in[10];
    const float* w3r = (const float*)d_in[11];
    const float* fc1_w = (const float*)d_in[12];
    const float* fc1_b = (const float*)d_in[13];
    const float* fc2_w = (const float*)d_in[14];
    const float* fc2_b = (const float*)d_in[15];
    const float* cls_w = (const float*)d_in[16];
    const float* cls_b = (const float*)d_in[17];
    float* out = (float*)d_out;

    const int* src = ei;
    const int* dst = ei + N_EDGES;

    // ---- workspace layout ----
    char* wsp = (char*)d_ws;
    size_t used = 0;
    auto alloc = [&](size_t bytes) {
        char* p = wsp + used;
        used += (bytes + 255) & ~(size_t)255;
        return p;
    };
    int*   cnt    = (int*)alloc((size_t)N_NODES * 4);
    int*   rowptr = (int*)alloc((size_t)(N_NODES + 1) * 4);
    int*   excl   = (int*)alloc((size_t)N_NODES * 4);
    int*   partial= (int*)alloc((size_t)(SCAN_NB + 1) * 4);
    int*   cols   = (int*)alloc((size_t)N_EDGES * 4);
    unsigned short* rank = (unsigned short*)alloc((size_t)N_EDGES * 2);
    float* invdeg = (float*)alloc((size_t)N_NODES * 4);
    int*   gstart = (int*)alloc((size_t)(N_GRAPHS + 1) * 4);
    char*  R      = alloc((size_t)N_NODES * 256 * 2);           // overlay
    bf16*  AG     = (bf16*)R;
    bf16*  h1     = (bf16*)(R + (size_t)N_NODES * 128 * 2);
    bf16*  h2     = (bf16*)alloc((size_t)N_NODES * 256 * 2);
    bf16*  w1l_b  = (bf16*)alloc(128 * 64 * 2);
    bf16*  w1r_b  = (bf16*)alloc(128 * 64 * 2);
    bf16*  w2l_b  = (bf16*)alloc(256 * 128 * 2);
    bf16*  w2r_b  = (bf16*)alloc(256 * 128 * 2);
    bf16*  w3l_b  = (bf16*)alloc(512 * 256 * 2);
    bf16*  w3r_b  = (bf16*)alloc(512 * 256 * 2);
    float* pooled = (float*)alloc((size_t)N_GRAPHS * 512 * 4);
    float* z1     = (float*)alloc((size_t)N_GRAPHS * 256 * 4);
    float* z2     = (float*)alloc((size_t)N_GRAPHS * 128 * 4);

    if (ws_size < used) return;

    // ---- CSR build (one atomic pass) ----
    hipMemsetAsync(cnt, 0, (size_t)N_NODES * 4, stream);
    rank_kernel<<<(N_EDGES + 255) / 256, 256, 0, stream>>>(dst, cnt, rank);
    scan_blocks_kernel<<<SCAN_NB, 1024, 0, stream>>>(cnt, excl, partial);
    scan_partial_kernel<<<1, 128, 0, stream>>>(partial);
    scan_add_kernel<<<(N_NODES + 256) / 256, 256, 0, stream>>>(excl, partial, cnt, rowptr, invdeg);
    place2_kernel<<<(N_EDGES + 255) / 256, 256, 0, stream>>>(src, dst, rank, rowptr, cols);
    bounds_kernel<<<2, 160, 0, stream>>>(batch, gstart);

    // ---- weight prep ----
    wprep_kernel<<<(128 * 64 + 255) / 256, 256, 0, stream>>>(w1l, w1l_b, 128, 50, 64);
    wprep_kernel<<<(128 * 64 + 255) / 256, 256, 0, stream>>>(w1r, w1r_b, 128, 50, 64);
    wprep_kernel<<<(256 * 128 + 255) / 256, 256, 0, stream>>>(w2l, w2l_b, 256, 128, 128);
    wprep_kernel<<<(256 * 128 + 255) / 256, 256, 0, stream>>>(w2r, w2r_b, 256, 128, 128);
    wprep_kernel<<<(512 * 256 + 255) / 256, 256, 0, stream>>>(w3l, w3l_b, 512, 256, 256);
    wprep_kernel<<<(512 * 256 + 255) / 256, 256, 0, stream>>>(w3r, w3r_b, 512, 256, 256);

    const int MB = (N_NODES + 127) / 128;  // 782

    // ---- layer 1: 50 -> 128, leaky_relu ----
    agg1_kernel<<<N_NODES, 64, 0, stream>>>(x, rowptr, cols, invdeg, AG);
    mfma_gemm1<<<dim3(1, MB), 256, 0, stream>>>(
        AG, 64, 64, x, 50, 64, 50, w1l_b, w1r_b, b1, h1, N_NODES, 128);

    // ---- layer 2: 128 -> 256, relu ----
    aggv_kernel<128><<<(N_NODES * 16 + 255) / 256, 256, 0, stream>>>(h1, rowptr, cols, invdeg, AG);
    glds_gemm<0><<<dim3(2, MB), 256, 0, stream>>>(
        AG, h1, 128, w2l_b, w2r_b, b2, h2, N_NODES, 256, nullptr, nullptr);

    // ---- layer 3: 256 -> 512, relu, fused pooled sum ----
    aggv_kernel<256><<<(N_NODES * 32 + 255) / 256, 256, 0, stream>>>(h2, rowptr, cols, invdeg, AG);
    hipMemsetAsync(pooled, 0, (size_t)N_GRAPHS * 512 * 4, stream);
    glds_gemm<1><<<dim3(4, MB), 256, 0, stream>>>(
        AG, h2, 256, w3l_b, w3r_b, b3, nullptr, N_NODES, 512, batch, pooled);
    pool_finalize<<<N_GRAPHS, 512, 0, stream>>>(pooled, gstart);

    // ---- MLP head ----
    mlp_kernel<1><<<(N_GRAPHS * 256 + 255) / 256, 256, 0, stream>>>(
        pooled, fc1_w, fc1_b, z1, N_GRAPHS, 512, 256);
    mlp_kernel<1><<<(N_GRAPHS * 128 + 255) / 256, 256, 0, stream>>>(
        z1, fc2_w, fc2_b, z2, N_GRAPHS, 256, 128);
    mlp_kernel<0><<<(N_GRAPHS * 15 + 255) / 256, 256, 0, stream>>>(
        z2, cls_w, cls_b, out, N_GRAPHS, 128, 15);
}